// Round 6
// baseline (27355.063 us; speedup 1.0000x reference)
//
#include <hip/hip_runtime.h>

typedef unsigned short u16;
using f16x8 = __attribute__((ext_vector_type(8))) _Float16;  // 8 fp16 (4 VGPRs)
using f32x4 = __attribute__((ext_vector_type(4))) float;

#define V_N 16384
#define M_N 32768

__device__ __forceinline__ float h2f(u16 u) {
  _Float16 h; __builtin_memcpy(&h, &u, 2); return (float)h;
}
__device__ __forceinline__ u16 f2h(float f) {
  _Float16 h = (_Float16)f; u16 u; __builtin_memcpy(&u, &h, 2); return u;
}

// ---------- prep kernels ----------
// LDS-transpose weight permute: wp[o][t*256+c] = f2h(w[o][c*12+t]).
// grid = 3 layers * 256 o-rows; coalesced f32 reads, coalesced u16 writes.
__global__ __launch_bounds__(256) void perm2_k(const float* __restrict__ w, u16* __restrict__ wp) {
  __shared__ u16 l[3072];
  int o = blockIdx.x & 255, layer = blockIdx.x >> 8;
  int t = threadIdx.x;
  const float* src = w + ((size_t)layer * 256 + o) * 3072;
  u16* dst = wp + ((size_t)layer * 256 + o) * 3072;
  float2 v[6];
  #pragma unroll
  for (int q = 0; q < 6; ++q) v[q] = *(const float2*)(src + t * 12 + q * 2);
  const float* vf = (const float*)v;
  #pragma unroll
  for (int m = 0; m < 12; ++m) l[m * 256 + t] = f2h(vf[m]);   // c = t
  __syncthreads();
  unsigned* d32 = (unsigned*)dst;
  const unsigned* l32 = (const unsigned*)l;
  #pragma unroll
  for (int q = 0; q < 6; ++q) d32[t * 6 + q] = l32[t * 6 + q];
}

// flat f32 -> fp16 convert
__global__ __launch_bounds__(256) void cvt_k(const float* __restrict__ w, u16* __restrict__ wb, int n) {
  int i = blockIdx.x * 256 + threadIdx.x;
  if (i < n) wb[i] = f2h(w[i]);
}

// ---------- encoder block 0 conv (C_in=3, K=36), f32 in -> fp16 out ----------
__global__ __launch_bounds__(256) void enc0_k(const float* __restrict__ verts, const int* __restrict__ sp,
                                              const float* __restrict__ w0, u16* __restrict__ y) {
  __shared__ float xs[32][36];
  int t = threadIdx.x;
  int r0 = blockIdx.x * 32;
  for (int s = t; s < 32 * 12; s += 256) {
    int row = s / 12, tt = s - row * 12;
    int gr = r0 + row;
    int b = gr >> 14, v = gr & (V_N - 1);
    int j = sp[tt * V_N + v];
    const float* p = verts + ((long)b * V_N + j) * 3;
    xs[row][tt]      = p[0];
    xs[row][12 + tt] = p[1];
    xs[row][24 + tt] = p[2];
  }
  __syncthreads();
  float w[36];
  #pragma unroll
  for (int k = 0; k < 36; ++k) w[k] = w0[t * 36 + k];
  for (int row = 0; row < 32; ++row) {
    float a = 0.f;
    #pragma unroll
    for (int k = 0; k < 36; ++k) a += w[k] * xs[row][k];
    y[(long)(r0 + row) * 256 + t] = f2h(a);
  }
}

// ---------- staged MFMA GEMM: per-l full-row LDS staging, 512 thr, tile 128M x 256N ----------
// Y[M x Ostore](fp16) = gatherA[M x (L*C)] * Wt^T (+f32 bias) (+fused BN stats).
// Gather: row = b*V + sp[l*V+v]; dense: row = bm+srow, P0 (l==0) / P1 (l>=1).
// Staging scale: if scl0 -> scale all l by scl0[b][c]; else if scl1 -> scale l>=1 by scl1[b][c].
__global__ __launch_bounds__(512, 2) void gemm2_k(
    const u16* __restrict__ P0, const u16* __restrict__ P1, int lda,
    const int* __restrict__ sp, int L, int C,
    const u16* __restrict__ Wt, int ldw,
    const float* __restrict__ scl0, const float* __restrict__ scl1,
    u16* __restrict__ Yb, const float* __restrict__ bias, int Ostore,
    float* __restrict__ stats)
{
  __shared__ __align__(16) u16 lA[128 * 256];   // 64KB, row-major C elems/row, XOR-swizzled 16B segs
  const int tid  = threadIdx.x;
  const int wave = tid >> 6, lane = tid & 63;
  const int wm = (wave & 1) * 64, wn = (wave >> 1) * 64;
  const int lr = lane & 15, lq = lane >> 4;
  const int bm = blockIdx.x * 128;
  const int batch = bm >> 14;
  const int srow = tid >> 2, slot = tid & 3;
  const int spt = C >> 5;          // 16B segs staged per thread (8 for C=256, 4 for C=128)
  const int KC  = C >> 5;          // K-chunks of 32 per l
  const int TK  = L * KC;
  const bool gat = (sp != nullptr);

  // staging scale vector (per-thread fixed channel set)
  f16x8 sg[8];
  const float* sclA = scl0 ? scl0 : scl1;
  if (sclA) {
    #pragma unroll
    for (int j = 0; j < 8; ++j) if (j < spt) {
      const float* s = sclA + batch * 256 + (slot * spt + j) * 8;
      f16x8 tv;
      #pragma unroll
      for (int e = 0; e < 8; ++e) tv[e] = (_Float16)s[e];
      sg[j] = tv;
    }
  }

  // B fragment pointers (k-flat: element offset step*32)
  const u16* bp[4];
  #pragma unroll
  for (int nt = 0; nt < 4; ++nt) bp[nt] = Wt + (long)(wn + nt * 16 + lr) * ldw + lq * 8;

  // ---- prologue: stage l=0 rows into regs, prefetch idx, B steps 0..1 ----
  const long rowbase = gat ? ((long)batch * V_N * lda) : 0;
  const int vloc = (bm & (V_N - 1)) + srow;
  f16x8 r[8];
  {
    const u16* b0;
    if (gat) b0 = P0 + rowbase + (long)sp[vloc] * lda;
    else     b0 = P0 + (long)(bm + srow) * lda;
    #pragma unroll
    for (int j = 0; j < 8; ++j) if (j < spt) r[j] = *(const f16x8*)(b0 + (slot * spt + j) * 8);
  }
  int idx_nxt = (gat && L > 1) ? sp[V_N + vloc] : 0;

  f16x8 fbv[2][4];
  #pragma unroll
  for (int s = 0; s < 2; ++s)
    #pragma unroll
    for (int nt = 0; nt < 4; ++nt) fbv[s][nt] = *(const f16x8*)(bp[nt] + s * 32);

  f32x4 acc[4][4];
  #pragma unroll
  for (int i = 0; i < 4; ++i)
    #pragma unroll
    for (int j = 0; j < 4; ++j) acc[i][j] = (f32x4){0.f, 0.f, 0.f, 0.f};

  for (int l = 0; l < L; ++l) {
    __syncthreads();                       // consumers of previous l done (drains r-loads too)
    const bool scale_now = (scl0 != nullptr) || (scl1 != nullptr && l >= 1);
    #pragma unroll
    for (int j = 0; j < 8; ++j) if (j < spt) {
      f16x8 rv = r[j];
      if (scale_now) rv = rv * sg[j];
      int ss = ((slot * spt + j) ^ (srow & 7)) * 8;
      *(f16x8*)(&lA[srow * C + ss]) = rv;
    }
    __syncthreads();                       // LDS ready
    // issue next-l staging AFTER the barrier (so the drain doesn't serialize it)
    if (l + 1 < L) {
      const u16* nb;
      if (gat) nb = P0 + rowbase + (long)idx_nxt * lda;
      else { const u16* Pn = P1 ? P1 : P0; nb = Pn + (long)(bm + srow) * lda; }
      #pragma unroll
      for (int j = 0; j < 8; ++j) if (j < spt) r[j] = *(const f16x8*)(nb + (slot * spt + j) * 8);
      if (gat && l + 2 < L) idx_nxt = sp[(long)(l + 2) * V_N + vloc];
    }
    // A-frag 1-ahead ping-pong from LDS; B depth-2 ping-pong from global (L2)
    f16x8 afA[4], afB[4];
    #pragma unroll
    for (int mt = 0; mt < 4; ++mt) {
      int row = wm + mt * 16 + lr;
      afA[mt] = *(const f16x8*)(&lA[row * C + (((0 * 4 + lq) ^ (row & 7)) * 8)]);
    }
    for (int kc = 0; kc < KC; ++kc) {
      int gs = l * KC + kc;
      f16x8* cur = (kc & 1) ? afB : afA;
      f16x8* nxt = (kc & 1) ? afA : afB;
      if (kc + 1 < KC) {
        #pragma unroll
        for (int mt = 0; mt < 4; ++mt) {
          int row = wm + mt * 16 + lr;
          nxt[mt] = *(const f16x8*)(&lA[row * C + ((((kc + 1) * 4 + lq) ^ (row & 7)) * 8)]);
        }
      }
      f16x8 bf[4];
      #pragma unroll
      for (int nt = 0; nt < 4; ++nt) bf[nt] = fbv[gs & 1][nt];
      #pragma unroll
      for (int mt = 0; mt < 4; ++mt)
        #pragma unroll
        for (int nt = 0; nt < 4; ++nt)
          acc[mt][nt] = __builtin_amdgcn_mfma_f32_16x16x32_f16(cur[mt], bf[nt], acc[mt][nt], 0, 0, 0);
      int ns = gs + 2;
      if (ns < TK) {
        #pragma unroll
        for (int nt = 0; nt < 4; ++nt) fbv[ns & 1][nt] = *(const f16x8*)(bp[nt] + (long)ns * 32);
      }
    }
  }

  // epilogue: C/D layout col=lane&15, row=(lane>>4)*4+reg [guide m89]; fused stats
  #pragma unroll
  for (int nt = 0; nt < 4; ++nt) {
    int col = wn + nt * 16 + lr;
    if (col < Ostore) {
      float bv = bias ? bias[col] : 0.f;
      float s1 = 0.f, s2 = 0.f;
      #pragma unroll
      for (int mt = 0; mt < 4; ++mt) {
        #pragma unroll
        for (int rg = 0; rg < 4; ++rg) {
          int row = bm + wm + mt * 16 + lq * 4 + rg;
          float v = acc[mt][nt][rg] + bv;
          Yb[(long)row * Ostore + col] = f2h(v);
          s1 += v; s2 += v * v;
        }
      }
      if (stats) {
        s1 += __shfl_xor(s1, 16); s1 += __shfl_xor(s1, 32);
        s2 += __shfl_xor(s2, 16); s2 += __shfl_xor(s2, 32);
        if (lq == 0) {
          atomicAdd(&stats[col], s1);
          atomicAdd(&stats[Ostore + col], s2);
        }
      }
    }
  }
}

// ---------- stats for enc0 output (O=256), vectorized ----------
__global__ __launch_bounds__(256) void stats2_k(const u16* __restrict__ y, float* __restrict__ st) {
  __shared__ float s1L[256], s2L[256];
  int tid = threadIdx.x;
  int ci = (tid & 63) * 4;
  int r0 = blockIdx.x * 64 + (tid >> 6);
  float a1[4] = {0,0,0,0}, a2[4] = {0,0,0,0};
  for (int it = 0; it < 16; ++it) {
    long i = ((long)r0 + it * 4) * 256 + ci;
    uint2 pv = *(const uint2*)(y + i);
    float v0 = h2f((u16)(pv.x & 0xffff)), v1 = h2f((u16)(pv.x >> 16));
    float v2 = h2f((u16)(pv.y & 0xffff)), v3 = h2f((u16)(pv.y >> 16));
    a1[0] += v0; a1[1] += v1; a1[2] += v2; a1[3] += v3;
    a2[0] += v0*v0; a2[1] += v1*v1; a2[2] += v2*v2; a2[3] += v3*v3;
  }
  s1L[tid] = 0.f; s2L[tid] = 0.f;
  __syncthreads();
  #pragma unroll
  for (int j = 0; j < 4; ++j) { atomicAdd(&s1L[ci + j], a1[j]); atomicAdd(&s2L[ci + j], a2[j]); }
  __syncthreads();
  atomicAdd(&st[tid], s1L[tid]);
  atomicAdd(&st[256 + tid], s2L[tid]);
}

// ---------- vectorized BN+ReLU (+fp16 residual, optional per-channel resid scale) (+SE sums) ----------
__global__ __launch_bounds__(256) void bnrelu2_k(
    const u16* __restrict__ y, const float* __restrict__ st,
    const float* __restrict__ g, const float* __restrict__ be,
    const u16* __restrict__ resid, const float* __restrict__ rscale,
    u16* __restrict__ ob, float* __restrict__ ses, int O)
{
  __shared__ float sL[256];
  int tid = threadIdx.x;
  int tpr = O >> 2;
  int rpi = 256 / tpr;
  int ci = (tid & (tpr - 1)) * 4;
  int row0 = blockIdx.x * (rpi * 16);
  int r0 = row0 + (tid / tpr);
  int b = row0 >> 14;
  float mean[4], sc[4], sh[4], rs[4];
  #pragma unroll
  for (int j = 0; j < 4; ++j) {
    int c = ci + j;
    float m = st[c] * (1.f / 32768.f);
    float var = st[O + c] * (1.f / 32768.f) - m * m;
    mean[j] = m;
    sc[j] = rsqrtf(fmaxf(var, 0.f) + 1e-5f) * g[c];
    sh[j] = be[c];
    rs[j] = rscale ? rscale[b * 256 + c] : 1.f;
  }
  float ss[4] = {0,0,0,0};
  for (int it = 0; it < 16; ++it) {
    long i = ((long)r0 + (long)it * rpi) * O + ci;
    uint2 pv = *(const uint2*)(y + i);
    float v[4];
    v[0] = fmaxf((h2f((u16)(pv.x & 0xffff)) - mean[0]) * sc[0] + sh[0], 0.f);
    v[1] = fmaxf((h2f((u16)(pv.x >> 16))    - mean[1]) * sc[1] + sh[1], 0.f);
    v[2] = fmaxf((h2f((u16)(pv.y & 0xffff)) - mean[2]) * sc[2] + sh[2], 0.f);
    v[3] = fmaxf((h2f((u16)(pv.y >> 16))    - mean[3]) * sc[3] + sh[3], 0.f);
    if (resid) {
      uint2 rv = *(const uint2*)(resid + i);
      v[0] += h2f((u16)(rv.x & 0xffff)) * rs[0]; v[1] += h2f((u16)(rv.x >> 16)) * rs[1];
      v[2] += h2f((u16)(rv.y & 0xffff)) * rs[2]; v[3] += h2f((u16)(rv.y >> 16)) * rs[3];
    }
    uint2 pk;
    pk.x = (unsigned)f2h(v[0]) | ((unsigned)f2h(v[1]) << 16);
    pk.y = (unsigned)f2h(v[2]) | ((unsigned)f2h(v[3]) << 16);
    *(uint2*)(ob + i) = pk;
    #pragma unroll
    for (int j = 0; j < 4; ++j) ss[j] += v[j];
  }
  if (ses) {
    sL[tid] = 0.f;
    __syncthreads();
    #pragma unroll
    for (int j = 0; j < 4; ++j) atomicAdd(&sL[ci + j], ss[j]);
    __syncthreads();
    atomicAdd(&ses[b * O + tid], sL[tid]);
  }
}

// ---------- SE gate ----------
__global__ void se_k(const float* __restrict__ ses, const float* __restrict__ w1,
                     const float* __restrict__ w2, float* __restrict__ sig)
{
  __shared__ float s[256];
  __shared__ float h[32];
  int b = blockIdx.x, t = threadIdx.x;
  s[t] = ses[b * 256 + t] * (1.f / 16384.f);
  __syncthreads();
  if (t < 32) {
    float a = 0.f;
    for (int c = 0; c < 256; ++c) a += w1[t * 256 + c] * s[c];
    h[t] = fmaxf(a, 0.f);
  }
  __syncthreads();
  float a = 0.f;
  #pragma unroll
  for (int r = 0; r < 32; ++r) a += w2[t * 32 + r] * h[r];
  sig[b * 256 + t] = 1.f / (1.f + expf(-a));
}

// ---------- x = out * sig (single use: decoder input materialization) ----------
__global__ __launch_bounds__(256) void scale_k(const u16* __restrict__ t, const float* __restrict__ sig,
                                               u16* __restrict__ xb)
{
  long i = ((long)blockIdx.x * 256 + threadIdx.x) * 4;
  int b = (int)(i >> 22);
  int c = (int)(i & 255);
  uint2 pv = *(const uint2*)(t + i);
  const float* sgp = sig + b * 256 + c;
  float v0 = h2f((u16)(pv.x & 0xffff)) * sgp[0];
  float v1 = h2f((u16)(pv.x >> 16))    * sgp[1];
  float v2 = h2f((u16)(pv.y & 0xffff)) * sgp[2];
  float v3 = h2f((u16)(pv.y >> 16))    * sgp[3];
  uint2 pk;
  pk.x = (unsigned)f2h(v0) | ((unsigned)f2h(v1) << 16);
  pk.y = (unsigned)f2h(v2) | ((unsigned)f2h(v3) << 16);
  *(uint2*)(xb + i) = pk;
}

// ---------- final head ----------
__global__ __launch_bounds__(256) void cls3_k(const u16* __restrict__ h2, const float* __restrict__ w,
                                              const float* __restrict__ b, float* __restrict__ out)
{
  __shared__ float ws[64];
  int t = threadIdx.x;
  if (t < 64) ws[t] = w[t];
  __syncthreads();
  int r = blockIdx.x * 256 + t;
  const u16* p = h2 + (long)r * 64;
  float a = b[0];
  #pragma unroll
  for (int c = 0; c < 64; ++c) a += ws[c] * h2f(p[c]);
  out[r] = a;
}

extern "C" void kernel_launch(void* const* d_in, const int* in_sizes, int n_in,
                              void* d_out, int out_size, void* d_ws, size_t ws_size,
                              hipStream_t stream)
{
  (void)in_sizes; (void)n_in; (void)out_size; (void)ws_size;
  const float* verts   = (const float*)d_in[0];
  const int*   spirals = (const int*)d_in[1];
  const float* enc0_w  = (const float*)d_in[2];
  const float* enc0_g  = (const float*)d_in[4];
  const float* enc0_be = (const float*)d_in[5];
  const float* enc_w   = (const float*)d_in[6];
  const float* enc_g   = (const float*)d_in[8];
  const float* enc_be  = (const float*)d_in[9];
  const float* se_w1   = (const float*)d_in[10];
  const float* se_w2   = (const float*)d_in[11];
  const float* skip_w  = (const float*)d_in[12];
  const float* skip_b  = (const float*)d_in[13];
  const float* dec_w   = (const float*)d_in[14];
  const float* dec_g   = (const float*)d_in[16];
  const float* dec_be  = (const float*)d_in[17];
  const float* cls1_w  = (const float*)d_in[18];
  const float* cls1_g  = (const float*)d_in[20];
  const float* cls1_be = (const float*)d_in[21];
  const float* cls2_w  = (const float*)d_in[22];
  const float* cls2_g  = (const float*)d_in[24];
  const float* cls2_be = (const float*)d_in[25];
  const float* cls3_w  = (const float*)d_in[26];
  const float* cls3_b  = (const float*)d_in[27];

  // --- workspace (~107 MB) ---
  char* p = (char*)d_ws;
  auto alloc = [&](size_t n) { char* q = p; p += (n + 255) & ~(size_t)255; return q; };
  u16* wpe   = (u16*)alloc((size_t)6 * 256 * 3072 * 2);
  u16* skip_wb = (u16*)alloc((size_t)3 * 256 * 512 * 2);
  u16* cls1_wb = (u16*)alloc((size_t)256 * 256 * 2);   // zero-padded to 256 rows
  u16* wp6     = (u16*)alloc((size_t)256 * 128 * 2);   // zero-padded to 256 rows
  float* stats = (float*)alloc(2048);
  float* sesum = (float*)alloc(2048);                  // contiguous after stats
  float* sig   = (float*)alloc(4 * 2048);              // sig_i = sig + i*512
  u16* out0 = (u16*)alloc((size_t)M_N * 256 * 2);
  u16* out1 = (u16*)alloc((size_t)M_N * 256 * 2);
  u16* out2 = (u16*)alloc((size_t)M_N * 256 * 2);
  u16* ct   = (u16*)alloc((size_t)M_N * 256 * 2);      // conv temp; aliases out3
  u16* tb   = (u16*)alloc((size_t)M_N * 256 * 2);
  u16* xd   = (u16*)alloc((size_t)M_N * 256 * 2);
  u16* outs[4] = {out0, out1, out2, ct};

  // prep
  perm2_k<<<768, 256, 0, stream>>>(enc_w, wpe);
  perm2_k<<<768, 256, 0, stream>>>(dec_w, wpe + (size_t)3 * 256 * 3072);
  cvt_k<<<1536, 256, 0, stream>>>(skip_w, skip_wb, 3 * 256 * 512);
  hipMemsetAsync(cls1_wb, 0, 256 * 256 * 2, stream);
  cvt_k<<<128, 256, 0, stream>>>(cls1_w, cls1_wb, 128 * 256);
  hipMemsetAsync(wp6, 0, 256 * 128 * 2, stream);
  cvt_k<<<32, 256, 0, stream>>>(cls2_w, wp6, 64 * 128);

  // ---- encoder block 0 ----
  hipMemsetAsync(stats, 0, 4096, stream);
  enc0_k<<<1024, 256, 0, stream>>>(verts, spirals, enc0_w, ct);
  stats2_k<<<512, 256, 0, stream>>>(ct, stats);
  bnrelu2_k<<<512, 256, 0, stream>>>(ct, stats, enc0_g, enc0_be, nullptr, nullptr, out0, sesum, 256);
  se_k<<<2, 256, 0, stream>>>(sesum, se_w1, se_w2, sig);

  // ---- encoder blocks 1..3 (x_{i-1} = out_{i-1} * sig_{i-1}, fused into staging/resid) ----
  for (int i = 1; i < 4; ++i) {
    hipMemsetAsync(stats, 0, 4096, stream);
    gemm2_k<<<256, 512, 0, stream>>>(outs[i - 1], nullptr, 256,
                                     spirals + (size_t)i * V_N * 12, 12, 256,
                                     wpe + (size_t)(i - 1) * 256 * 3072, 3072,
                                     sig + (i - 1) * 512, nullptr,
                                     ct, nullptr, 256, stats);
    bnrelu2_k<<<512, 256, 0, stream>>>(ct, stats, enc_g + (i - 1) * 256, enc_be + (i - 1) * 256,
                                       outs[i - 1], sig + (i - 1) * 512, outs[i], sesum, 256);
    se_k<<<2, 256, 0, stream>>>(sesum, se_w1 + (size_t)i * 32 * 256,
                                se_w2 + (size_t)i * 256 * 32, sig + i * 512);
  }

  // decoder input x = out3 * sig3 (materialized once; out3 aliases ct)
  scale_k<<<8192, 256, 0, stream>>>(ct, sig + 3 * 512, xd);

  // ---- decoder blocks ----
  for (int i = 0; i < 3; ++i) {
    gemm2_k<<<256, 512, 0, stream>>>(xd, outs[2 - i], 256, nullptr, 2, 256,
                                     skip_wb + (size_t)i * 256 * 512, 512,
                                     nullptr, sig + (2 - i) * 512,
                                     tb, skip_b + i * 256, 256, nullptr);          // x1 -> tb
    hipMemsetAsync(stats, 0, 4096, stream);
    gemm2_k<<<256, 512, 0, stream>>>(tb, nullptr, 256,
                                     spirals + (size_t)(2 - i) * V_N * 12, 12, 256,
                                     wpe + (size_t)(3 + i) * 256 * 3072, 3072,
                                     nullptr, nullptr,
                                     outs[2 - i], nullptr, 256, stats);            // conv -> out[2-i]
    bnrelu2_k<<<512, 256, 0, stream>>>(outs[2 - i], stats, dec_g + i * 256, dec_be + i * 256,
                                       tb, nullptr, xd, nullptr, 256);             // x -> xd
  }

  // ---- classifier ----
  hipMemsetAsync(stats, 0, 4096, stream);
  gemm2_k<<<256, 512, 0, stream>>>(xd, nullptr, 256, nullptr, 1, 256,
                                   cls1_wb, 256, nullptr, nullptr, ct, nullptr, 128, stats);
  bnrelu2_k<<<256, 256, 0, stream>>>(ct, stats, cls1_g, cls1_be, nullptr, nullptr, ct, nullptr, 128);
  hipMemsetAsync(stats, 0, 4096, stream);
  gemm2_k<<<256, 512, 0, stream>>>(ct, nullptr, 128, nullptr, 1, 128,
                                   wp6, 128, nullptr, nullptr, tb, nullptr, 64, stats);
  bnrelu2_k<<<128, 256, 0, stream>>>(tb, stats, cls2_g, cls2_be, nullptr, nullptr, tb, nullptr, 64);
  cls3_k<<<128, 256, 0, stream>>>(tb, cls3_w, cls3_b, (float*)d_out);
}

// Round 7
// 1546.392 us; speedup vs baseline: 17.6896x; 17.6896x over previous
//
#include <hip/hip_runtime.h>

typedef unsigned short u16;
using f16x8 = __attribute__((ext_vector_type(8))) _Float16;  // 8 fp16 (4 VGPRs)
using f32x4 = __attribute__((ext_vector_type(4))) float;

#define V_N 16384
#define M_N 32768

__device__ __forceinline__ float h2f(u16 u) {
  _Float16 h; __builtin_memcpy(&h, &u, 2); return (float)h;
}
__device__ __forceinline__ u16 f2h(float f) {
  _Float16 h = (_Float16)f; u16 u; __builtin_memcpy(&u, &h, 2); return u;
}

// ---------- prep kernels ----------
// LDS-transpose weight permute: wp[o][t*256+c] = f2h(w[o][c*12+t])
__global__ __launch_bounds__(256) void perm2_k(const float* __restrict__ w, u16* __restrict__ wp) {
  __shared__ u16 l[3072];
  int o = blockIdx.x & 255, layer = blockIdx.x >> 8;
  int t = threadIdx.x;
  const float* src = w + ((size_t)layer * 256 + o) * 3072;
  u16* dst = wp + ((size_t)layer * 256 + o) * 3072;
  float2 v[6];
  #pragma unroll
  for (int q = 0; q < 6; ++q) v[q] = *(const float2*)(src + t * 12 + q * 2);
  const float* vf = (const float*)v;
  #pragma unroll
  for (int m = 0; m < 12; ++m) l[m * 256 + t] = f2h(vf[m]);   // c = t
  __syncthreads();
  unsigned* d32 = (unsigned*)dst;
  const unsigned* l32 = (const unsigned*)l;
  #pragma unroll
  for (int q = 0; q < 6; ++q) d32[t * 6 + q] = l32[t * 6 + q];
}

// flat f32 -> fp16 convert
__global__ __launch_bounds__(256) void cvt_k(const float* __restrict__ w, u16* __restrict__ wb, int n) {
  int i = blockIdx.x * 256 + threadIdx.x;
  if (i < n) wb[i] = f2h(w[i]);
}

// ---------- encoder block 0 conv (C_in=3, K=36), f32 in -> fp16 out ----------
__global__ __launch_bounds__(256) void enc0_k(const float* __restrict__ verts, const int* __restrict__ sp,
                                              const float* __restrict__ w0, u16* __restrict__ y) {
  __shared__ float xs[32][36];
  int t = threadIdx.x;
  int r0 = blockIdx.x * 32;
  for (int s = t; s < 32 * 12; s += 256) {
    int row = s / 12, tt = s - row * 12;
    int gr = r0 + row;
    int b = gr >> 14, v = gr & (V_N - 1);
    int j = sp[tt * V_N + v];
    const float* p = verts + ((long)b * V_N + j) * 3;
    xs[row][tt]      = p[0];
    xs[row][12 + tt] = p[1];
    xs[row][24 + tt] = p[2];
  }
  __syncthreads();
  float w[36];
  #pragma unroll
  for (int k = 0; k < 36; ++k) w[k] = w0[t * 36 + k];
  for (int row = 0; row < 32; ++row) {
    float a = 0.f;
    #pragma unroll
    for (int k = 0; k < 36; ++k) a += w[k] * xs[row][k];
    y[(long)(r0 + row) * 256 + t] = f2h(a);
  }
}

// ---------- staged MFMA GEMM (templated: ALL inner indices compile-time, no scratch) ----------
// Y[M x Ostore](fp16) = gatherA[M x (L*CT)] * Wt^T (+f32 bias) (+fused BN stats).
// Gather: row = b*V + sp[l*V+v]; dense: row = bm+srow, P0 (l==0) / P1 (l>=1).
// Staging scale: scl0 -> scale all l by scl0[b][c]; else scl1 -> scale l>=1 by scl1[b][c].
// Block 512 thr = 8 waves, tile 128M x 256N; LDS holds one l-tap of 128 gathered rows.
template<int CT>
__global__ __launch_bounds__(512) void gemm2_k(
    const u16* __restrict__ P0, const u16* __restrict__ P1, int lda,
    const int* __restrict__ sp, int L,
    const u16* __restrict__ Wt, int ldw,
    const float* __restrict__ scl0, const float* __restrict__ scl1,
    u16* __restrict__ Yb, const float* __restrict__ bias, int Ostore,
    float* __restrict__ stats)
{
  constexpr int KC  = CT >> 5;     // K-chunks of 32 per tap (8 for CT=256, 4 for CT=128); even
  constexpr int SPT = CT >> 5;     // 16B segs staged per thread
  __shared__ __align__(16) u16 lA[128 * CT];
  const int tid  = threadIdx.x;
  const int wave = tid >> 6, lane = tid & 63;
  const int wm = (wave & 1) * 64, wn = (wave >> 1) * 64;
  const int lr = lane & 15, lq = lane >> 4;
  const int bm = blockIdx.x * 128;
  const int batch = bm >> 14;
  const int srow = tid >> 2, slot = tid & 3;
  const bool gat = (sp != nullptr);
  const int TK = L * KC;

  // staging scale vector (per-thread fixed channel set)
  f16x8 sg[SPT];
  const float* sclA = scl0 ? scl0 : scl1;
  if (sclA) {
    #pragma unroll
    for (int j = 0; j < SPT; ++j) {
      const float* s = sclA + batch * 256 + (slot * SPT + j) * 8;
      f16x8 tv;
      #pragma unroll
      for (int e = 0; e < 8; ++e) tv[e] = (_Float16)s[e];
      sg[j] = tv;
    }
  }

  // B fragment pointers
  const u16* bp[4];
  #pragma unroll
  for (int nt = 0; nt < 4; ++nt) bp[nt] = Wt + (long)(wn + nt * 16 + lr) * ldw + lq * 8;

  // ---- prologue: stage l=0 row into regs, prefetch idx, B gs=0,1 ----
  const long rowbase = gat ? ((long)batch * V_N * lda) : 0;
  const int vloc = (bm & (V_N - 1)) + srow;
  f16x8 r[SPT];
  {
    const u16* b0;
    if (gat) b0 = P0 + rowbase + (long)sp[vloc] * lda;
    else     b0 = P0 + (long)(bm + srow) * lda;
    #pragma unroll
    for (int j = 0; j < SPT; ++j) r[j] = *(const f16x8*)(b0 + (slot * SPT + j) * 8);
  }
  int idx_nxt = (gat && L > 1) ? sp[V_N + vloc] : 0;

  f16x8 bv0[4], bv1[4];
  #pragma unroll
  for (int nt = 0; nt < 4; ++nt) bv0[nt] = *(const f16x8*)(bp[nt]);
  #pragma unroll
  for (int nt = 0; nt < 4; ++nt) bv1[nt] = *(const f16x8*)(bp[nt] + 32);

  f32x4 acc[4][4];
  #pragma unroll
  for (int i = 0; i < 4; ++i)
    #pragma unroll
    for (int j = 0; j < 4; ++j) acc[i][j] = (f32x4){0.f, 0.f, 0.f, 0.f};

  for (int l = 0; l < L; ++l) {
    __syncthreads();                       // previous-l LDS consumers done
    const bool scale_now = (scl0 != nullptr) || (scl1 != nullptr && l >= 1);
    #pragma unroll
    for (int j = 0; j < SPT; ++j) {
      f16x8 rv = r[j];
      if (scale_now) rv = rv * sg[j];
      int ss = ((slot * SPT + j) ^ (srow & 7)) * 8;
      *(f16x8*)(&lA[srow * CT + ss]) = rv;
    }
    __syncthreads();                       // LDS ready
    // issue next-l staging AFTER the barrier (full MFMA phase to complete)
    if (l + 1 < L) {
      const u16* nb;
      if (gat) nb = P0 + rowbase + (long)idx_nxt * lda;
      else { const u16* Pn = P1 ? P1 : P0; nb = Pn + (long)(bm + srow) * lda; }
      #pragma unroll
      for (int j = 0; j < SPT; ++j) r[j] = *(const f16x8*)(nb + (slot * SPT + j) * 8);
      if (gat && l + 2 < L) idx_nxt = sp[(long)(l + 2) * V_N + vloc];
    }
    // A-frag + B depth-2 ping-pong, all names compile-time
    f16x8 a0[4], a1[4];
    #pragma unroll
    for (int mt = 0; mt < 4; ++mt) {
      int row = wm + mt * 16 + lr;
      a0[mt] = *(const f16x8*)(&lA[row * CT + ((lq ^ (row & 7)) * 8)]);
    }
    #pragma unroll
    for (int kc = 0; kc < KC; kc += 2) {
      const int gs = l * KC + kc;
      #pragma unroll
      for (int mt = 0; mt < 4; ++mt) {
        int row = wm + mt * 16 + lr;
        a1[mt] = *(const f16x8*)(&lA[row * CT + ((((kc + 1) * 4 + lq) ^ (row & 7)) * 8)]);
      }
      f16x8 t0[4];
      if (gs + 2 < TK) {
        #pragma unroll
        for (int nt = 0; nt < 4; ++nt) t0[nt] = *(const f16x8*)(bp[nt] + (long)(gs + 2) * 32);
      }
      #pragma unroll
      for (int mt = 0; mt < 4; ++mt)
        #pragma unroll
        for (int nt = 0; nt < 4; ++nt)
          acc[mt][nt] = __builtin_amdgcn_mfma_f32_16x16x32_f16(a0[mt], bv0[nt], acc[mt][nt], 0, 0, 0);
      if (kc + 2 < KC) {
        #pragma unroll
        for (int mt = 0; mt < 4; ++mt) {
          int row = wm + mt * 16 + lr;
          a0[mt] = *(const f16x8*)(&lA[row * CT + ((((kc + 2) * 4 + lq) ^ (row & 7)) * 8)]);
        }
      }
      f16x8 t1[4];
      if (gs + 3 < TK) {
        #pragma unroll
        for (int nt = 0; nt < 4; ++nt) t1[nt] = *(const f16x8*)(bp[nt] + (long)(gs + 3) * 32);
      }
      #pragma unroll
      for (int mt = 0; mt < 4; ++mt)
        #pragma unroll
        for (int nt = 0; nt < 4; ++nt)
          acc[mt][nt] = __builtin_amdgcn_mfma_f32_16x16x32_f16(a1[mt], bv1[nt], acc[mt][nt], 0, 0, 0);
      #pragma unroll
      for (int nt = 0; nt < 4; ++nt) { bv0[nt] = t0[nt]; bv1[nt] = t1[nt]; }
    }
  }

  // epilogue: C/D layout col=lane&15, row=(lane>>4)*4+reg [guide m89]; fused stats
  #pragma unroll
  for (int nt = 0; nt < 4; ++nt) {
    int col = wn + nt * 16 + lr;
    if (col < Ostore) {
      float bv = bias ? bias[col] : 0.f;
      float s1 = 0.f, s2 = 0.f;
      #pragma unroll
      for (int mt = 0; mt < 4; ++mt) {
        #pragma unroll
        for (int rg = 0; rg < 4; ++rg) {
          int row = bm + wm + mt * 16 + lq * 4 + rg;
          float v = acc[mt][nt][rg] + bv;
          Yb[(long)row * Ostore + col] = f2h(v);
          s1 += v; s2 += v * v;
        }
      }
      if (stats) {
        s1 += __shfl_xor(s1, 16); s1 += __shfl_xor(s1, 32);
        s2 += __shfl_xor(s2, 16); s2 += __shfl_xor(s2, 32);
        if (lq == 0) {
          atomicAdd(&stats[col], s1);
          atomicAdd(&stats[Ostore + col], s2);
        }
      }
    }
  }
}

// ---------- stats for enc0 output (O=256), vectorized ----------
__global__ __launch_bounds__(256) void stats2_k(const u16* __restrict__ y, float* __restrict__ st) {
  __shared__ float s1L[256], s2L[256];
  int tid = threadIdx.x;
  int ci = (tid & 63) * 4;
  int r0 = blockIdx.x * 64 + (tid >> 6);
  float a1[4] = {0,0,0,0}, a2[4] = {0,0,0,0};
  for (int it = 0; it < 16; ++it) {
    long i = ((long)r0 + it * 4) * 256 + ci;
    uint2 pv = *(const uint2*)(y + i);
    float v0 = h2f((u16)(pv.x & 0xffff)), v1 = h2f((u16)(pv.x >> 16));
    float v2 = h2f((u16)(pv.y & 0xffff)), v3 = h2f((u16)(pv.y >> 16));
    a1[0] += v0; a1[1] += v1; a1[2] += v2; a1[3] += v3;
    a2[0] += v0*v0; a2[1] += v1*v1; a2[2] += v2*v2; a2[3] += v3*v3;
  }
  s1L[tid] = 0.f; s2L[tid] = 0.f;
  __syncthreads();
  #pragma unroll
  for (int j = 0; j < 4; ++j) { atomicAdd(&s1L[ci + j], a1[j]); atomicAdd(&s2L[ci + j], a2[j]); }
  __syncthreads();
  atomicAdd(&st[tid], s1L[tid]);
  atomicAdd(&st[256 + tid], s2L[tid]);
}

// ---------- vectorized BN+ReLU (+fp16 residual, optional per-channel resid scale) (+SE sums) ----------
__global__ __launch_bounds__(256) void bnrelu2_k(
    const u16* __restrict__ y, const float* __restrict__ st,
    const float* __restrict__ g, const float* __restrict__ be,
    const u16* __restrict__ resid, const float* __restrict__ rscale,
    u16* __restrict__ ob, float* __restrict__ ses, int O)
{
  __shared__ float sL[256];
  int tid = threadIdx.x;
  int tpr = O >> 2;
  int rpi = 256 / tpr;
  int ci = (tid & (tpr - 1)) * 4;
  int row0 = blockIdx.x * (rpi * 16);
  int r0 = row0 + (tid / tpr);
  int b = row0 >> 14;
  float mean[4], sc[4], sh[4], rs[4];
  #pragma unroll
  for (int j = 0; j < 4; ++j) {
    int c = ci + j;
    float m = st[c] * (1.f / 32768.f);
    float var = st[O + c] * (1.f / 32768.f) - m * m;
    mean[j] = m;
    sc[j] = rsqrtf(fmaxf(var, 0.f) + 1e-5f) * g[c];
    sh[j] = be[c];
    rs[j] = rscale ? rscale[b * 256 + c] : 1.f;
  }
  float ss[4] = {0,0,0,0};
  for (int it = 0; it < 16; ++it) {
    long i = ((long)r0 + (long)it * rpi) * O + ci;
    uint2 pv = *(const uint2*)(y + i);
    float v[4];
    v[0] = fmaxf((h2f((u16)(pv.x & 0xffff)) - mean[0]) * sc[0] + sh[0], 0.f);
    v[1] = fmaxf((h2f((u16)(pv.x >> 16))    - mean[1]) * sc[1] + sh[1], 0.f);
    v[2] = fmaxf((h2f((u16)(pv.y & 0xffff)) - mean[2]) * sc[2] + sh[2], 0.f);
    v[3] = fmaxf((h2f((u16)(pv.y >> 16))    - mean[3]) * sc[3] + sh[3], 0.f);
    if (resid) {
      uint2 rv = *(const uint2*)(resid + i);
      v[0] += h2f((u16)(rv.x & 0xffff)) * rs[0]; v[1] += h2f((u16)(rv.x >> 16)) * rs[1];
      v[2] += h2f((u16)(rv.y & 0xffff)) * rs[2]; v[3] += h2f((u16)(rv.y >> 16)) * rs[3];
    }
    uint2 pk;
    pk.x = (unsigned)f2h(v[0]) | ((unsigned)f2h(v[1]) << 16);
    pk.y = (unsigned)f2h(v[2]) | ((unsigned)f2h(v[3]) << 16);
    *(uint2*)(ob + i) = pk;
    #pragma unroll
    for (int j = 0; j < 4; ++j) ss[j] += v[j];
  }
  if (ses) {
    sL[tid] = 0.f;
    __syncthreads();
    #pragma unroll
    for (int j = 0; j < 4; ++j) atomicAdd(&sL[ci + j], ss[j]);
    __syncthreads();
    atomicAdd(&ses[b * O + tid], sL[tid]);
  }
}

// ---------- SE gate ----------
__global__ void se_k(const float* __restrict__ ses, const float* __restrict__ w1,
                     const float* __restrict__ w2, float* __restrict__ sig)
{
  __shared__ float s[256];
  __shared__ float h[32];
  int b = blockIdx.x, t = threadIdx.x;
  s[t] = ses[b * 256 + t] * (1.f / 16384.f);
  __syncthreads();
  if (t < 32) {
    float a = 0.f;
    for (int c = 0; c < 256; ++c) a += w1[t * 256 + c] * s[c];
    h[t] = fmaxf(a, 0.f);
  }
  __syncthreads();
  float a = 0.f;
  #pragma unroll
  for (int r = 0; r < 32; ++r) a += w2[t * 32 + r] * h[r];
  sig[b * 256 + t] = 1.f / (1.f + expf(-a));
}

// ---------- x = out * sig (single use: decoder input materialization) ----------
__global__ __launch_bounds__(256) void scale_k(const u16* __restrict__ t, const float* __restrict__ sig,
                                               u16* __restrict__ xb)
{
  long i = ((long)blockIdx.x * 256 + threadIdx.x) * 4;
  int b = (int)(i >> 22);
  int c = (int)(i & 255);
  uint2 pv = *(const uint2*)(t + i);
  const float* sgp = sig + b * 256 + c;
  float v0 = h2f((u16)(pv.x & 0xffff)) * sgp[0];
  float v1 = h2f((u16)(pv.x >> 16))    * sgp[1];
  float v2 = h2f((u16)(pv.y & 0xffff)) * sgp[2];
  float v3 = h2f((u16)(pv.y >> 16))    * sgp[3];
  uint2 pk;
  pk.x = (unsigned)f2h(v0) | ((unsigned)f2h(v1) << 16);
  pk.y = (unsigned)f2h(v2) | ((unsigned)f2h(v3) << 16);
  *(uint2*)(xb + i) = pk;
}

// ---------- final head ----------
__global__ __launch_bounds__(256) void cls3_k(const u16* __restrict__ h2, const float* __restrict__ w,
                                              const float* __restrict__ b, float* __restrict__ out)
{
  __shared__ float ws[64];
  int t = threadIdx.x;
  if (t < 64) ws[t] = w[t];
  __syncthreads();
  int r = blockIdx.x * 256 + t;
  const u16* p = h2 + (long)r * 64;
  float a = b[0];
  #pragma unroll
  for (int c = 0; c < 64; ++c) a += ws[c] * h2f(p[c]);
  out[r] = a;
}

extern "C" void kernel_launch(void* const* d_in, const int* in_sizes, int n_in,
                              void* d_out, int out_size, void* d_ws, size_t ws_size,
                              hipStream_t stream)
{
  (void)in_sizes; (void)n_in; (void)out_size; (void)ws_size;
  const float* verts   = (const float*)d_in[0];
  const int*   spirals = (const int*)d_in[1];
  const float* enc0_w  = (const float*)d_in[2];
  const float* enc0_g  = (const float*)d_in[4];
  const float* enc0_be = (const float*)d_in[5];
  const float* enc_w   = (const float*)d_in[6];
  const float* enc_g   = (const float*)d_in[8];
  const float* enc_be  = (const float*)d_in[9];
  const float* se_w1   = (const float*)d_in[10];
  const float* se_w2   = (const float*)d_in[11];
  const float* skip_w  = (const float*)d_in[12];
  const float* skip_b  = (const float*)d_in[13];
  const float* dec_w   = (const float*)d_in[14];
  const float* dec_g   = (const float*)d_in[16];
  const float* dec_be  = (const float*)d_in[17];
  const float* cls1_w  = (const float*)d_in[18];
  const float* cls1_g  = (const float*)d_in[20];
  const float* cls1_be = (const float*)d_in[21];
  const float* cls2_w  = (const float*)d_in[22];
  const float* cls2_g  = (const float*)d_in[24];
  const float* cls2_be = (const float*)d_in[25];
  const float* cls3_w  = (const float*)d_in[26];
  const float* cls3_b  = (const float*)d_in[27];

  // --- workspace (~107 MB) ---
  char* p = (char*)d_ws;
  auto alloc = [&](size_t n) { char* q = p; p += (n + 255) & ~(size_t)255; return q; };
  u16* wpe   = (u16*)alloc((size_t)6 * 256 * 3072 * 2);
  u16* skip_wb = (u16*)alloc((size_t)3 * 256 * 512 * 2);
  u16* cls1_wb = (u16*)alloc((size_t)256 * 256 * 2);   // zero-padded to 256 rows
  u16* wp6     = (u16*)alloc((size_t)256 * 128 * 2);   // zero-padded to 256 rows
  float* stats = (float*)alloc(2048);
  float* sesum = (float*)alloc(2048);                  // contiguous after stats
  float* sig   = (float*)alloc(4 * 2048);              // sig_i = sig + i*512
  u16* out0 = (u16*)alloc((size_t)M_N * 256 * 2);
  u16* out1 = (u16*)alloc((size_t)M_N * 256 * 2);
  u16* out2 = (u16*)alloc((size_t)M_N * 256 * 2);
  u16* ct   = (u16*)alloc((size_t)M_N * 256 * 2);      // conv temp; aliases out3
  u16* tb   = (u16*)alloc((size_t)M_N * 256 * 2);
  u16* xd   = (u16*)alloc((size_t)M_N * 256 * 2);
  u16* outs[4] = {out0, out1, out2, ct};

  // prep
  perm2_k<<<768, 256, 0, stream>>>(enc_w, wpe);
  perm2_k<<<768, 256, 0, stream>>>(dec_w, wpe + (size_t)3 * 256 * 3072);
  cvt_k<<<1536, 256, 0, stream>>>(skip_w, skip_wb, 3 * 256 * 512);
  hipMemsetAsync(cls1_wb, 0, 256 * 256 * 2, stream);
  cvt_k<<<128, 256, 0, stream>>>(cls1_w, cls1_wb, 128 * 256);
  hipMemsetAsync(wp6, 0, 256 * 128 * 2, stream);
  cvt_k<<<32, 256, 0, stream>>>(cls2_w, wp6, 64 * 128);

  // ---- encoder block 0 ----
  hipMemsetAsync(stats, 0, 4096, stream);
  enc0_k<<<1024, 256, 0, stream>>>(verts, spirals, enc0_w, ct);
  stats2_k<<<512, 256, 0, stream>>>(ct, stats);
  bnrelu2_k<<<512, 256, 0, stream>>>(ct, stats, enc0_g, enc0_be, nullptr, nullptr, out0, sesum, 256);
  se_k<<<2, 256, 0, stream>>>(sesum, se_w1, se_w2, sig);

  // ---- encoder blocks 1..3 (x_{i-1} = out_{i-1} * sig_{i-1}, fused into staging/resid) ----
  for (int i = 1; i < 4; ++i) {
    hipMemsetAsync(stats, 0, 4096, stream);
    gemm2_k<256><<<256, 512, 0, stream>>>(outs[i - 1], nullptr, 256,
                                          spirals + (size_t)i * V_N * 12, 12,
                                          wpe + (size_t)(i - 1) * 256 * 3072, 3072,
                                          sig + (i - 1) * 512, nullptr,
                                          ct, nullptr, 256, stats);
    bnrelu2_k<<<512, 256, 0, stream>>>(ct, stats, enc_g + (i - 1) * 256, enc_be + (i - 1) * 256,
                                       outs[i - 1], sig + (i - 1) * 512, outs[i], sesum, 256);
    se_k<<<2, 256, 0, stream>>>(sesum, se_w1 + (size_t)i * 32 * 256,
                                se_w2 + (size_t)i * 256 * 32, sig + i * 512);
  }

  // decoder input x = out3 * sig3 (materialized once; out3 aliases ct)
  scale_k<<<8192, 256, 0, stream>>>(ct, sig + 3 * 512, xd);

  // ---- decoder blocks ----
  for (int i = 0; i < 3; ++i) {
    gemm2_k<256><<<256, 512, 0, stream>>>(xd, outs[2 - i], 256, nullptr, 2,
                                          skip_wb + (size_t)i * 256 * 512, 512,
                                          nullptr, sig + (2 - i) * 512,
                                          tb, skip_b + i * 256, 256, nullptr);       // x1 -> tb
    hipMemsetAsync(stats, 0, 4096, stream);
    gemm2_k<256><<<256, 512, 0, stream>>>(tb, nullptr, 256,
                                          spirals + (size_t)(2 - i) * V_N * 12, 12,
                                          wpe + (size_t)(3 + i) * 256 * 3072, 3072,
                                          nullptr, nullptr,
                                          outs[2 - i], nullptr, 256, stats);          // conv -> out[2-i]
    bnrelu2_k<<<512, 256, 0, stream>>>(outs[2 - i], stats, dec_g + i * 256, dec_be + i * 256,
                                       tb, nullptr, xd, nullptr, 256);                // x -> xd
  }

  // ---- classifier ----
  hipMemsetAsync(stats, 0, 4096, stream);
  gemm2_k<256><<<256, 512, 0, stream>>>(xd, nullptr, 256, nullptr, 1,
                                        cls1_wb, 256, nullptr, nullptr, ct, nullptr, 128, stats);
  bnrelu2_k<<<256, 256, 0, stream>>>(ct, stats, cls1_g, cls1_be, nullptr, nullptr, ct, nullptr, 128);
  hipMemsetAsync(stats, 0, 4096, stream);
  gemm2_k<128><<<256, 512, 0, stream>>>(ct, nullptr, 128, nullptr, 1,
                                        wp6, 128, nullptr, nullptr, tb, nullptr, 64, stats);
  bnrelu2_k<<<128, 256, 0, stream>>>(tb, stats, cls2_g, cls2_be, nullptr, nullptr, tb, nullptr, 64);
  cls3_k<<<128, 256, 0, stream>>>(tb, cls3_w, cls3_b, (float*)d_out);
}